// Round 2
// 1034.164 us; speedup vs baseline: 1.2591x; 1.2591x over previous
//
#include <hip/hip_runtime.h>

typedef _Float16 f16;
typedef _Float16 half8 __attribute__((ext_vector_type(8)));
typedef float floatx4 __attribute__((ext_vector_type(4)));
typedef unsigned long long u64;
typedef unsigned int u32;
typedef unsigned int u32v4 __attribute__((ext_vector_type(4)));

// Problem sizes
#define NB 64
#define NS 256
#define NE 512
#define NH 512
#define NG 2048   // 4H
#define NN 4096   // 2 dirs * 4H

// ---------------- workspace layout (bytes) ----------------
// xp     : f16 [16384][4096]   134217728   gate preacts (bias folded), both dirs
// emb_h  : f16 [16384][512]     16777216   (dead after k_gemm; h_ext overlays it)
// w_cat  : f16 [4096][512]       4194304   [w_ih_f ; w_ih_b]
// whh    : f16 [2][2048][512]    4194304
// h_seq  : f16 [64][256][1024]  33554432   [h_f | h_b] for attention
// bias   : f32 [4096]              16384
// h_ext  : u32 [2par][2dir][8bg][8b][512]  524288  tagged exchange, overlays emb_h
#define OFF_XP     0
#define OFF_EMB    134217728
#define OFF_WCAT   150994944
#define OFF_WHH    155189248
#define OFF_HSEQ   159383552
#define OFF_BIAS   193200128
#define OFF_HEXT   OFF_EMB

__device__ __forceinline__ void cbar() {  // compiler-only reorder barrier
  asm volatile("" ::: "memory");
}
// overflow-safe fast tanh: 1 - 2/(1+e^{2x}); x=+inf -> 1, x=-inf -> -1, no NaN
__device__ __forceinline__ float fast_tanh(float x) {
  float e = __expf(2.f * x);
  return 1.f - 2.f / (1.f + e);
}

// ---------------- prep: combine biases ----------------
__global__ void k_prep(float* bias,
                       const float* bihf, const float* bhhf,
                       const float* bihb, const float* bhhb) {
  int id = blockIdx.x * 256 + threadIdx.x;       // 4096 threads
  bias[id] = (id < 2048) ? (bihf[id] + bhhf[id]) : (bihb[id - 2048] + bhhb[id - 2048]);
}

// ---------------- zero the tagged exchange buffer (after k_gemm) ----------------
__global__ void k_zero(uint4* p) {
  uint4 z; z.x = 0; z.y = 0; z.z = 0; z.w = 0;
  p[blockIdx.x * 256 + threadIdx.x] = z;         // 128 blocks -> 524288 B
}

// ---------------- embedding gather + f32->f16 cast ----------------
__global__ void k_embed(const int* __restrict__ x, const float* __restrict__ embed,
                        f16* __restrict__ emb_h) {
  int gid = blockIdx.x * 256 + threadIdx.x;      // 1048576 threads, 8 halves each
  size_t base = (size_t)gid * 8;
  int r = (int)(base >> 9);
  int e = (int)(base & 511);
  int xi = x[r];
  const float4* src = (const float4*)(embed + (size_t)xi * 512 + e);
  float4 a = src[0], b = src[1];
  half8 h;
  h[0] = (f16)a.x; h[1] = (f16)a.y; h[2] = (f16)a.z; h[3] = (f16)a.w;
  h[4] = (f16)b.x; h[5] = (f16)b.y; h[6] = (f16)b.z; h[7] = (f16)b.w;
  *(half8*)(emb_h + base) = h;
}

// ---------------- weight casts ----------------
__global__ void k_wcast(const float* __restrict__ wihf, const float* __restrict__ wihb,
                        const float* __restrict__ whhf, const float* __restrict__ whhb,
                        f16* __restrict__ w_cat, f16* __restrict__ whh) {
  int gid = blockIdx.x * 256 + threadIdx.x;      // 524288 threads, 8 halves each
  size_t i8 = (size_t)gid * 8;
  const float* src;
  f16* dst;
  if (i8 < 2097152) {                            // w_cat [4096][512]
    size_t n = i8 >> 9, k = i8 & 511;
    src = (n < 2048 ? wihf + n * 512 : wihb + (n - 2048) * 512) + k;
    dst = w_cat + i8;
  } else {                                       // whh [2][2048][512]
    size_t i2 = i8 - 2097152;
    int dir = (int)(i2 >> 20);
    size_t rk = i2 & 1048575;
    src = (dir ? whhb : whhf) + rk;
    dst = whh + i2;
  }
  float4 a = *(const float4*)src, b = *(const float4*)(src + 4);
  half8 h;
  h[0] = (f16)a.x; h[1] = (f16)a.y; h[2] = (f16)a.z; h[3] = (f16)a.w;
  h[4] = (f16)b.x; h[5] = (f16)b.y; h[6] = (f16)b.z; h[7] = (f16)b.w;
  *(half8*)dst = h;
}

// ---------------- xproj GEMM: [16384,512] @ [4096,512]^T -> f16, +bias ----------
__global__ __launch_bounds__(256) void k_gemm(const f16* __restrict__ A,
                                              const f16* __restrict__ Bw,
                                              const float* __restrict__ bias,
                                              f16* __restrict__ xp) {
  __shared__ __align__(16) f16 As[128 * 32];
  __shared__ __align__(16) f16 Bs[128 * 32];
  const int t = threadIdx.x;
  const int m0 = blockIdx.x * 128;
  const int n0 = blockIdx.y * 128;
  const int w = t >> 6, l = t & 63;
  const int wm = w >> 1, wn = w & 1;
  const int l15 = l & 15, q8 = (l >> 4) * 8;

  floatx4 acc[4][4];
#pragma unroll
  for (int mi = 0; mi < 4; mi++)
#pragma unroll
    for (int ni = 0; ni < 4; ni++) {
      acc[mi][ni][0] = 0.f; acc[mi][ni][1] = 0.f;
      acc[mi][ni][2] = 0.f; acc[mi][ni][3] = 0.f;
    }

  for (int kt = 0; kt < 16; kt++) {
#pragma unroll
    for (int i = 0; i < 2; i++) {
      int c = t + 256 * i;
      int row = c >> 2, kc = (c & 3) * 8;
      *(uint4*)&As[row * 32 + kc] = *(const uint4*)(A + (size_t)(m0 + row) * 512 + kt * 32 + kc);
      *(uint4*)&Bs[row * 32 + kc] = *(const uint4*)(Bw + (size_t)(n0 + row) * 512 + kt * 32 + kc);
    }
    __syncthreads();
    half8 af[4], bf[4];
#pragma unroll
    for (int mi = 0; mi < 4; mi++)
      af[mi] = *(const half8*)&As[(wm * 64 + mi * 16 + l15) * 32 + q8];
#pragma unroll
    for (int ni = 0; ni < 4; ni++)
      bf[ni] = *(const half8*)&Bs[(wn * 64 + ni * 16 + l15) * 32 + q8];
#pragma unroll
    for (int mi = 0; mi < 4; mi++)
#pragma unroll
      for (int ni = 0; ni < 4; ni++)
        acc[mi][ni] = __builtin_amdgcn_mfma_f32_16x16x32_f16(af[mi], bf[ni], acc[mi][ni], 0, 0, 0);
    __syncthreads();
  }

#pragma unroll
  for (int ni = 0; ni < 4; ni++) {
    int ng = n0 + wn * 64 + ni * 16 + l15;
    float bv = bias[ng];
#pragma unroll
    for (int mi = 0; mi < 4; mi++) {
      int mg = m0 + wm * 64 + mi * 16 + (l >> 4) * 4;
#pragma unroll
      for (int r = 0; r < 4; r++)
        xp[(size_t)(mg + r) * 4096 + ng] = (f16)(acc[mi][ni][r] + bv);
    }
  }
}

// ---------------- recurrent kernel ----------------
// 256 blocks: blk = dir + 2*bg + 16*jg. Sync group = 16 blocks sharing (dir,bg).
// FLAGLESS self-validating exchange: each h element is published as a u32
//   (tag<<16 | f16_bits), tag = step index of the h value. Consumers poll the
//   data itself (system-scope relaxed loads, IF-coherent) until every dword of
//   their slice carries tag==st. No flags, no vmcnt ack, no separate flag poll.
// Back-pressure: parity double-buffer, distance-2 safe — a producer publishes
//   tag st+3 into a parity slab only after reading all tags==st+2, which
//   implies every block already finished its st+1 read of that slab.
// Tags are 16-bit, 256 steps -> no wraparound/ABA.
__global__ __launch_bounds__(256) void k_rec(const f16* __restrict__ whh,
                                             const f16* __restrict__ xp,
                                             u32* __restrict__ h_ext,
                                             f16* __restrict__ h_seq) {
  const int blk = blockIdx.x;
  const int dir = blk & 1;
  const int bg  = (blk >> 1) & 7;
  const int jg  = blk >> 4;
  const int t = threadIdx.x;
  const int w = t >> 6, l = t & 63;
  const int l15 = l & 15, q = l >> 4;
  const int lb = l15 & 7;                 // batch row, clamped (cols 8-15 dup/discarded)

  // A-frags: 32 w_hh rows per wave (2 m-tiles of 16), resident whole kernel
  half8 fa[2][16];
  {
    const f16* wb = whh + ((size_t)dir * 2048 + w * 512 + jg * 32 + l15) * 512;
#pragma unroll
    for (int mi = 0; mi < 2; mi++)
#pragma unroll
      for (int kt = 0; kt < 16; kt++)
        fa[mi][kt] = *(const half8*)(wb + (size_t)mi * 16 * 512 + kt * 32 + q * 8);
  }

  // hbuf: [kt][b][32 halves], kt-stride padded 256->264 halves (512->528 B) so
  // the cooperative fill's kt-major writes rotate across banks (16-way -> ~2-way).
  __shared__ __align__(16) f16 hbuf[16 * 264];
  __shared__ float zbuf[4][32][19];            // [gate][hu_local][b(pad)]
  __shared__ __align__(16) f16 hstage[8][32];  // [b][hu_local] (h_seq staging only)

  float creg = 0.f;
  const int uhu = t & 31, ub = t >> 5;         // cell-update mapping (256 cells)

  // xp address: row=(8bg+lb)*256+s, col=dir*2048+w*512+jg*32 + mi*16 + q*4
  const size_t xrowb = ((size_t)(8 * bg + lb) * 256) * (size_t)NN +
                       (size_t)dir * 2048 + w * 512 + jg * 32 + q * 4;

  // exchange-slab word index bases (4096 u32 per (par,dir,bg) slab)
  const int slab_rd_base = (dir * 8 + bg) * 4096;       // + par*2*8*4096
  // consumer slice: thread t covers u32 words [cl_src32, cl_src32+16)
  const int cl_b = t >> 5;                  // 0..7
  const int cl_i = t & 31;                  // 16-word chunk index
  const int cl_src32 = cl_b * 512 + cl_i * 16;
  const int cl_kt = cl_i >> 1;
  const int cl_sel = (cl_i & 1) * 16;
  const int cl_dst = cl_kt * 264 + cl_b * 32 + cl_sel;  // halves (padded layout)
  // producer slot: cell (ub, uhu) -> word ub*512 + jg*32 + uhu
  const int pub_idx = ub * 512 + jg * 32 + uhu;

#pragma unroll 1
  for (int st = 0; st < NS; st++) {
    const int s = dir ? (255 - st) : st;

    // prefetch xp (hides HBM latency under the data poll)
    const f16* xpp = xp + xrowb + (size_t)s * NN;
    uint2 xv0 = *(const uint2*)xpp;
    uint2 xv1 = *(const uint2*)(xpp + 16);
    cbar();

    // ---- poll + load h: data is self-validating (tag==st in every dword) ----
    {
      const u32* slab32 = h_ext + ((st & 1) * 16 * 4096) + slab_rd_base;
      const u64* sp = (const u64*)(slab32 + cl_src32);
      const u64 tmask = 0xffff0000ffff0000ull;
      const u64 texp = ((u64)(u32)st << 16) | ((u64)(u32)st << 48);
      u64 wv0, wv1, wv2, wv3, wv4, wv5, wv6, wv7;
      while (true) {
        wv0 = __hip_atomic_load(sp + 0, __ATOMIC_RELAXED, __HIP_MEMORY_SCOPE_SYSTEM);
        wv1 = __hip_atomic_load(sp + 1, __ATOMIC_RELAXED, __HIP_MEMORY_SCOPE_SYSTEM);
        wv2 = __hip_atomic_load(sp + 2, __ATOMIC_RELAXED, __HIP_MEMORY_SCOPE_SYSTEM);
        wv3 = __hip_atomic_load(sp + 3, __ATOMIC_RELAXED, __HIP_MEMORY_SCOPE_SYSTEM);
        wv4 = __hip_atomic_load(sp + 4, __ATOMIC_RELAXED, __HIP_MEMORY_SCOPE_SYSTEM);
        wv5 = __hip_atomic_load(sp + 5, __ATOMIC_RELAXED, __HIP_MEMORY_SCOPE_SYSTEM);
        wv6 = __hip_atomic_load(sp + 6, __ATOMIC_RELAXED, __HIP_MEMORY_SCOPE_SYSTEM);
        wv7 = __hip_atomic_load(sp + 7, __ATOMIC_RELAXED, __HIP_MEMORY_SCOPE_SYSTEM);
        bool ok = ((wv0 & tmask) == texp) & ((wv1 & tmask) == texp) &
                  ((wv2 & tmask) == texp) & ((wv3 & tmask) == texp) &
                  ((wv4 & tmask) == texp) & ((wv5 & tmask) == texp) &
                  ((wv6 & tmask) == texp) & ((wv7 & tmask) == texp);
        if (ok) break;
        __builtin_amdgcn_s_sleep(1);
      }
      // extract f16 payloads -> 8 packed dwords -> padded LDS
      u32v4 d0, d1;
      d0[0] = (u32)(wv0 & 0xffffu) | ((u32)((wv0 >> 32) & 0xffffu) << 16);
      d0[1] = (u32)(wv1 & 0xffffu) | ((u32)((wv1 >> 32) & 0xffffu) << 16);
      d0[2] = (u32)(wv2 & 0xffffu) | ((u32)((wv2 >> 32) & 0xffffu) << 16);
      d0[3] = (u32)(wv3 & 0xffffu) | ((u32)((wv3 >> 32) & 0xffffu) << 16);
      d1[0] = (u32)(wv4 & 0xffffu) | ((u32)((wv4 >> 32) & 0xffffu) << 16);
      d1[1] = (u32)(wv5 & 0xffffu) | ((u32)((wv5 >> 32) & 0xffffu) << 16);
      d1[2] = (u32)(wv6 & 0xffffu) | ((u32)((wv6 >> 32) & 0xffffu) << 16);
      d1[3] = (u32)(wv7 & 0xffffu) | ((u32)((wv7 >> 32) & 0xffffu) << 16);
      *(u32v4*)&hbuf[cl_dst + 0] = d0;
      *(u32v4*)&hbuf[cl_dst + 8] = d1;
    }
    __syncthreads();

    // z = w_hh @ h : 32 MFMAs/wave, split into even/odd-kt chains (half the
    // dependent-MFMA latency; f32 adds at the end restore the sum)
    floatx4 a0e, a0o, a1e, a1o;
    a0e[0]=0.f;a0e[1]=0.f;a0e[2]=0.f;a0e[3]=0.f;
    a0o[0]=0.f;a0o[1]=0.f;a0o[2]=0.f;a0o[3]=0.f;
    a1e[0]=0.f;a1e[1]=0.f;a1e[2]=0.f;a1e[3]=0.f;
    a1o[0]=0.f;a1o[1]=0.f;a1o[2]=0.f;a1o[3]=0.f;
#pragma unroll
    for (int kt = 0; kt < 16; kt += 2) {
      half8 bf0 = *(const half8*)&hbuf[kt * 264 + lb * 32 + q * 8];
      half8 bf1 = *(const half8*)&hbuf[(kt + 1) * 264 + lb * 32 + q * 8];
      a0e = __builtin_amdgcn_mfma_f32_16x16x32_f16(fa[0][kt], bf0, a0e, 0, 0, 0);
      a1e = __builtin_amdgcn_mfma_f32_16x16x32_f16(fa[1][kt], bf0, a1e, 0, 0, 0);
      a0o = __builtin_amdgcn_mfma_f32_16x16x32_f16(fa[0][kt + 1], bf1, a0o, 0, 0, 0);
      a1o = __builtin_amdgcn_mfma_f32_16x16x32_f16(fa[1][kt + 1], bf1, a1o, 0, 0, 0);
    }
    floatx4 acc0 = a0e + a0o;
    floatx4 acc1 = a1e + a1o;

    // z + xp -> LDS gate exchange (D layout: row=q*4+r, col=l15)
    {
      const f16* x0 = (const f16*)&xv0;
      const f16* x1 = (const f16*)&xv1;
#pragma unroll
      for (int r = 0; r < 4; r++) {
        zbuf[w][q * 4 + r][l15]      = acc0[r] + (float)x0[r];
        zbuf[w][16 + q * 4 + r][l15] = acc1[r] + (float)x1[r];
      }
    }
    __syncthreads();

    // LSTM cell update: 1 cell/thread, c persistent in VGPR.
    // Publish tagged h DIRECTLY from the register (critical path), then stage
    // for h_seq (off critical path).
    {
      float iv = zbuf[0][uhu][ub];
      float fv = zbuf[1][uhu][ub];
      float gv = zbuf[2][uhu][ub];
      float ov = zbuf[3][uhu][ub];
      float ig = 1.f / (1.f + __expf(-iv));
      float fg = 1.f / (1.f + __expf(-fv));
      float og = 1.f / (1.f + __expf(-ov));
      creg = fg * creg + ig * fast_tanh(gv);
      f16 hh = (f16)(og * fast_tanh(creg));
      unsigned short hb = __builtin_bit_cast(unsigned short, hh);
      u32 word = (u32)hb | ((u32)(st + 1) << 16);
      u32* wslab = h_ext + (((st + 1) & 1) * 16 * 4096) + slab_rd_base;
      __hip_atomic_store(wslab + pub_idx, word, __ATOMIC_RELAXED,
                         __HIP_MEMORY_SCOPE_SYSTEM);
      hstage[ub][uhu] = hh;
    }
    __syncthreads();

    // h_seq for attention (plain stores, read only after kernel end)
    if (t < 64) {
      const int pb = t >> 3, pc = (t & 7) * 4;
      u64 hv = *(const u64*)&hstage[pb][pc];
      *(u64*)(h_seq + ((size_t)(8 * bg + pb) * 256 + s) * 1024 + dir * 512 + jg * 32 + pc) = hv;
    }
  }
}

// ---------------- attention pooling + lin1 + lin2 ----------------
__global__ __launch_bounds__(256) void k_attn(const f16* __restrict__ h_seq,
                                              const float* __restrict__ myw,
                                              const float* __restrict__ l1w,
                                              const float* __restrict__ l1b,
                                              const float* __restrict__ l2w,
                                              const float* __restrict__ l2b,
                                              float* __restrict__ out) {
  const int b = blockIdx.x;
  const int t = threadIdx.x;
  const int w = t >> 6, l = t & 63;
  float mw[16];
#pragma unroll
  for (int i = 0; i < 16; i += 4) {
    float4 v = *(const float4*)(myw + l * 16 + i);
    mw[i] = v.x; mw[i + 1] = v.y; mw[i + 2] = v.z; mw[i + 3] = v.w;
  }
  float pool[16];
#pragma unroll
  for (int i = 0; i < 16; i++) pool[i] = 0.f;
  float psum = 0.f;

  for (int s = w; s < NS; s += 4) {
    const f16* hp = h_seq + ((size_t)b * NS + s) * 1024 + l * 16;
    half8 h0 = *(const half8*)hp;
    half8 h1 = *(const half8*)(hp + 8);
    float hv[16];
#pragma unroll
    for (int i = 0; i < 8; i++) { hv[i] = (float)h0[i]; hv[8 + i] = (float)h1[i]; }
    float d = 0.f;
#pragma unroll
    for (int i = 0; i < 16; i++) d += hv[i] * mw[i];
#pragma unroll
    for (int off = 32; off > 0; off >>= 1) d += __shfl_xor(d, off);
    float p = __expf(tanhf(d));
    psum += p;
#pragma unroll
    for (int i = 0; i < 16; i++) pool[i] += p * hv[i];
  }

  __shared__ float zb[4][1024];
  __shared__ float ps[4];
  __shared__ float pooled[1024];
  __shared__ float h1s[512];
#pragma unroll
  for (int i = 0; i < 16; i++) zb[w][l * 16 + i] = pool[i];
  if (l == 0) ps[w] = psum;
  __syncthreads();
  float denom = ps[0] + ps[1] + ps[2] + ps[3];
  for (int d0 = t; d0 < 1024; d0 += 256)
    pooled[d0] = (zb[0][d0] + zb[1][d0] + zb[2][d0] + zb[3][d0]) / denom;
  __syncthreads();
  for (int r = t; r < 512; r += 256) {
    const float* wr = l1w + (size_t)r * 1024;
    float a = l1b[r];
    for (int k = 0; k < 1024; k += 4) {
      float4 wv = *(const float4*)(wr + k);
      a += wv.x * pooled[k] + wv.y * pooled[k + 1] + wv.z * pooled[k + 2] + wv.w * pooled[k + 3];
    }
    h1s[r] = a;
  }
  __syncthreads();
  if (t < 20) {
    const float* wr = l2w + t * 512;
    float a = l2b[t];
    for (int k = 0; k < 512; k++) a += h1s[k] * wr[k];
    out[b * 20 + t] = a;
  }
}

extern "C" void kernel_launch(void* const* d_in, const int* in_sizes, int n_in,
                              void* d_out, int out_size, void* d_ws, size_t ws_size,
                              hipStream_t stream) {
  (void)in_sizes; (void)n_in; (void)out_size; (void)ws_size;
  const int*   x     = (const int*)d_in[0];
  const float* embed = (const float*)d_in[1];
  const float* wihf  = (const float*)d_in[2];
  const float* whhf  = (const float*)d_in[3];
  const float* bihf  = (const float*)d_in[4];
  const float* bhhf  = (const float*)d_in[5];
  const float* wihb  = (const float*)d_in[6];
  const float* whhb  = (const float*)d_in[7];
  const float* bihb  = (const float*)d_in[8];
  const float* bhhb  = (const float*)d_in[9];
  const float* myw   = (const float*)d_in[10];
  const float* l1w   = (const float*)d_in[11];
  const float* l1b   = (const float*)d_in[12];
  const float* l2w   = (const float*)d_in[13];
  const float* l2b   = (const float*)d_in[14];

  char* ws = (char*)d_ws;
  f16*   xp    = (f16*)(ws + OFF_XP);
  f16*   emb_h = (f16*)(ws + OFF_EMB);
  f16*   w_cat = (f16*)(ws + OFF_WCAT);
  f16*   whh   = (f16*)(ws + OFF_WHH);
  f16*   h_seq = (f16*)(ws + OFF_HSEQ);
  u32*   h_ext = (u32*)(ws + OFF_HEXT);
  float* bias  = (float*)(ws + OFF_BIAS);
  float* out   = (float*)d_out;

  k_prep<<<16, 256, 0, stream>>>(bias, bihf, bhhf, bihb, bhhb);
  k_embed<<<4096, 256, 0, stream>>>(x, embed, emb_h);
  k_wcast<<<2048, 256, 0, stream>>>(wihf, wihb, whhf, whhb, w_cat, whh);
  k_gemm<<<dim3(128, 32), 256, 0, stream>>>(emb_h, w_cat, bias, xp);
  k_zero<<<128, 256, 0, stream>>>((uint4*)(ws + OFF_HEXT));
  k_rec<<<256, 256, 0, stream>>>(whh, xp, h_ext, h_seq);
  k_attn<<<64, 256, 0, stream>>>(h_seq, myw, l1w, l1b, l2w, l2b, out);
}